// Round 3
// baseline (214.547 us; speedup 1.0000x reference)
//
#include <hip/hip_runtime.h>

typedef unsigned short USH;
typedef short s16x8 __attribute__((ext_vector_type(8)));
typedef float f32x4 __attribute__((ext_vector_type(4)));
typedef float f32x4v __attribute__((ext_vector_type(4)));
typedef unsigned int u32x4 __attribute__((ext_vector_type(4)));
// may_alias variants for ALL type-punned LDS/global accesses.
typedef s16x8 s16x8_a __attribute__((may_alias));
typedef f32x4v f32x4v_a __attribute__((may_alias));
typedef u32x4 u32x4_a __attribute__((may_alias));
typedef unsigned long long u64_a __attribute__((may_alias));

#if __has_builtin(__builtin_amdgcn_exp2f)
#define EXP2F(x) __builtin_amdgcn_exp2f(x)  // raw v_exp_f32, no legalization
#else
#define EXP2F(x) __builtin_exp2f(x)
#endif

__device__ __forceinline__ USH f2bf(float f) {
  union { float f; unsigned int i; } c; c.f = f;
  unsigned int x = c.i;
  return (USH)((x + 0x7FFFu + ((x >> 16) & 1u)) >> 16);
}
__device__ __forceinline__ unsigned int pk_bf16(float a, float b) {
#if __has_builtin(__builtin_amdgcn_cvt_pk_bf16_f32)
  typedef USH ush2 __attribute__((ext_vector_type(2)));
  union { ush2 v; unsigned int u; } r;
  r.v = __builtin_amdgcn_cvt_pk_bf16_f32(a, b);
  return r.u;
#else
  union { float f; unsigned int i; } ca, cb; ca.f = a; cb.f = b;
  return ((ca.i + 0x8000u) >> 16) | ((cb.i + 0x8000u) & 0xFFFF0000u);
#endif
}

__device__ __forceinline__ f32x4 mfma16(s16x8 a, s16x8 b, f32x4 c) {
  return __builtin_amdgcn_mfma_f32_16x16x32_bf16(a, b, c, 0, 0, 0);
}

// async global->LDS, 16B per lane; LDS dest semantics: wave base + lane*16.
#if __has_builtin(__builtin_amdgcn_global_load_lds)
__device__ __forceinline__ void gld_lds16(const USH* g, USH* l) {
  __builtin_amdgcn_global_load_lds(
      static_cast<const unsigned int __attribute__((address_space(1)))*>(
          (const void __attribute__((address_space(1)))*)g),
      static_cast<unsigned int __attribute__((address_space(3)))*>(
          (void __attribute__((address_space(3)))*)l),
      16, 0, 0);
}
#else
__device__ __forceinline__ void gld_lds16(const USH* g, USH* l) {
  *(s16x8_a*)l = *(const s16x8_a*)g;  // fallback: synchronous copy, same addresses
}
#endif

// ------------- prep: z<4 -> WT[n][k] = bf16(W[k][n]);  z==4 -> xb = bf16(x) -------------
__global__ __launch_bounds__(256) void prep(
    const float* __restrict__ Wq, const float* __restrict__ Wk,
    const float* __restrict__ Wv, const float* __restrict__ Wo,
    const float* __restrict__ x, USH* __restrict__ wsT, USH* __restrict__ xb) {
  __shared__ float tile[32][33];
  const int z = blockIdx.z;
  const int t = threadIdx.x;
  if (z == 4) {  // convert x: 256 blocks x 16384 floats
    const size_t b0 = ((size_t)blockIdx.y * 16 + blockIdx.x) * 16384;
    #pragma unroll
    for (int j = 0; j < 8; ++j) {
      const size_t i = b0 + (size_t)j * 2048 + t * 8;
      const f32x4v a = *(const f32x4v_a*)(x + i);
      const f32x4v b = *(const f32x4v_a*)(x + i + 4);
      u32x4 s;
      s.x = pk_bf16(a.x, a.y); s.y = pk_bf16(a.z, a.w);
      s.z = pk_bf16(b.x, b.y); s.w = pk_bf16(b.z, b.w);
      *(u32x4_a*)(xb + i) = s;
    }
    return;
  }
  const float* W = (z == 0) ? Wq : (z == 1) ? Wk : (z == 2) ? Wv : Wo;
  USH* WT = wsT + (size_t)z * 262144;
  const int n0 = blockIdx.x * 32, k0 = blockIdx.y * 32;
  const int tx = t & 31, ty = t >> 5;  // 32 x 8
  #pragma unroll
  for (int i = 0; i < 4; ++i)
    tile[ty + i * 8][tx] = W[(size_t)(k0 + ty + i * 8) * 512 + n0 + tx];
  __syncthreads();
  #pragma unroll
  for (int i = 0; i < 4; ++i)
    WT[(size_t)(n0 + ty + i * 8) * 512 + k0 + tx] = f2bf(tile[tx][ty + i * 8]);
}

// ---------------- GEMM: out = A[M,512](bf16) * WT^T + bias ----------------
// ROUND-13 PROVEN VERSION (round-14 operand-swap epilogue regressed −43us:
// per-lane b64/f32x4 stores put consecutive lanes 128B..2KB apart -> 16 cache
// lines per store inst vs 4 for the scalar-consecutive epilogue. Reverted.)
// MODE 0: float out[m*512+n] (d_out fp32).
// MODE 1: z==0 -> Q bf16 [B,H,S,Hd] scaled by sc*log2e; z==1 -> K [B,H,S,Hd];
//         z==2 -> V [B,H,Hd,S] (pre-transposed for attn).
// BK=64, register prefetch, 3 blocks/CU (768-block QKV dispatch single-pass).
template <int MODE>
__global__ __launch_bounds__(256, 3) void gemm_bias(
    const USH* __restrict__ A, const USH* __restrict__ BT0,
    const float* __restrict__ b0, const float* __restrict__ b1,
    const float* __restrict__ b2,
    USH* __restrict__ oQ, USH* __restrict__ oKV, float* __restrict__ oF) {
  __shared__ __align__(16) USH As[128 * 68];
  __shared__ __align__(16) USH Bs[128 * 68];
  const int z = blockIdx.z;
  const USH* BT = BT0 + (size_t)z * 262144;
  const float* bias = (z == 0) ? b0 : ((z == 1) ? b1 : b2);
  USH* outb = (z == 0) ? oQ : (oKV + (size_t)(z - 1) * 4194304);
  const float qs = (MODE == 1 && z == 0) ? 0.06375871528132839f : 1.0f;

  const int t = threadIdx.x;
  const int w = t >> 6, lane = t & 63;
  const int c = lane & 15, g = lane >> 4;
  const int wm = w & 1, wn = w >> 1;
  const int m0 = blockIdx.x * 128, n0 = blockIdx.y * 128;
  const int srow = t >> 1, scol = (t & 1) * 32;

  f32x4 acc[4][4] = {};

  const USH* Ap0 = A + (size_t)(m0 + srow) * 512 + scol;
  const USH* Bp0 = BT + (size_t)(n0 + srow) * 512 + scol;
  s16x8 pa[4], pb[4];
  #pragma unroll
  for (int j = 0; j < 4; ++j) {
    pa[j] = *(const s16x8_a*)(Ap0 + j * 8);
    pb[j] = *(const s16x8_a*)(Bp0 + j * 8);
  }

  for (int kt = 0; kt < 8; ++kt) {
    __syncthreads();
    #pragma unroll
    for (int j = 0; j < 4; ++j) {
      *(s16x8_a*)(As + srow * 68 + scol + j * 8) = pa[j];
      *(s16x8_a*)(Bs + srow * 68 + scol + j * 8) = pb[j];
    }
    const int ktn = (kt < 7) ? kt + 1 : kt;
    #pragma unroll
    for (int j = 0; j < 4; ++j) {
      pa[j] = *(const s16x8_a*)(Ap0 + ktn * 64 + j * 8);
      pb[j] = *(const s16x8_a*)(Bp0 + ktn * 64 + j * 8);
    }
    __syncthreads();
    #pragma unroll
    for (int ks = 0; ks < 2; ++ks) {
      s16x8 af[4], bfr[4];
      #pragma unroll
      for (int i = 0; i < 4; ++i) {
        af[i]  = *(const s16x8_a*)(As + (wm * 64 + i * 16 + c) * 68 + ks * 32 + g * 8);
        bfr[i] = *(const s16x8_a*)(Bs + (wn * 64 + i * 16 + c) * 68 + ks * 32 + g * 8);
      }
      #pragma unroll
      for (int mf = 0; mf < 4; ++mf)
        #pragma unroll
        for (int nf = 0; nf < 4; ++nf)
          acc[mf][nf] = mfma16(af[mf], bfr[nf], acc[mf][nf]);
    }
  }

  #pragma unroll
  for (int nf = 0; nf < 4; ++nf) {
    const int n = n0 + wn * 64 + nf * 16 + c;
    const float bv = bias[n];
    #pragma unroll
    for (int mf = 0; mf < 4; ++mf)
      #pragma unroll
      for (int r = 0; r < 4; ++r) {
        const int m = m0 + wm * 64 + mf * 16 + g * 4 + r;
        const float v = (acc[mf][nf][r] + bv) * qs;
        if (MODE == 0) {
          oF[(size_t)m * 512 + n] = v;
        } else {
          const int bb = m >> 12, s = m & 4095, h = n >> 6, hd = n & 63;
          if (z == 2)
            outb[(((size_t)(bb * 8 + h)) * 64 + hd) * 4096 + s] = f2bf(v);
          else
            outb[(((size_t)(bb * 8 + h)) * 4096 + s) * 64 + hd] = f2bf(v);
        }
      }
  }
}

// ---------------- flash attention v12: software-pipelined softmax+PV ----------------
// v10/v11 post-mortem: iteration time ~3860 cyc invariant to memory level
// (L3->L2, r0), LDS traffic (-36%, r1), and wave count (16->8/CU, r1) ->
// NOT a throughput limit. Work per SIMD/iter: MFMA 72x19.4 ~= 1400 cyc
// (matches MfmaUtil 31-36%), VALU ~400-800 -> ~50% of each iter is stall:
// the in-wave chain QK -> wait st -> exp2 -> pack -> Ps write/read -> PV
// serializes, and all waves sit in the same phase (barrier-synced), so the
// matrix pipe idles during softmax and vice versa.
// v12: pipeline one tile: issue QK(kt) MFMAs (no result wait), then process
// tile kt-1 (exp2/pack/Ps/PV) -- independent of the in-flight QK. Matrix pipe
// gets QK(kt)+PV(kt-1) back-to-back; softmax VALU + Ps DS round-trip hide
// under the MFMA drain. V is TRIPLE-buffered (PV reads kt-1 while DMA writes
// kt+1; 2 bufs would collide), K stays double-buffered. Unroll-2 gives static
// stA/stB register ping-pong (no dynamic register indexing).
// LDS: K 16K + V 24K + Ps 19K + lbuf 0.5K = 60928 B, 2 blocks/CU.
// Q pre-scaled by sc*log2e -> p = exp2(s). l = P.1 on the MFMA pipe.
__global__ __launch_bounds__(256, 2) void attn(const USH* __restrict__ Qbuf,
                                               const USH* __restrict__ kv,
                                               USH* __restrict__ att) {
  __shared__ __align__(16) USH Ks[2 * 4096];   // K tile kt in buf kt&1
  __shared__ __align__(16) USH Vt[3 * 4096];   // V tile kt in slot kt%3
  __shared__ __align__(16) USH Ps[4][32 * 76]; // per-wave [32 qrow][76 key-pad]
  __shared__ float lbuf[4][32];

  const int t = threadIdx.x;
  const int w = t >> 6, lane = t & 63;
  const int c = lane & 15, g = lane >> 4;
  // XCD-aware remap: each XCD owns 2 bh -> KV working set 2 MB <= L2 (kept
  // from v10: halves HBM fetch; harmless here, helps DMA latency margin).
  const int linear = blockIdx.x + (blockIdx.y << 5);
  const int xcd = linear & 7, idx = linear >> 3;
  const int bh = xcd + ((idx >> 5) << 3);
  const int bb = bh >> 3, hh = bh & 7;
  const size_t base = (size_t)bh * 262144;  // 4096*64
  const USH* Q = Qbuf + base;
  const USH* K = kv + base;                 // [S,Hd]
  const USH* V = kv + 4194304 + base;       // [Hd,S] (pre-transposed)
  const int q0 = (idx & 31) * 128 + w * 32;

  // Q fragments (B-operand of S^T): registers for the whole K loop
  s16x8 qf[2][2];  // [qi][kh]
  #pragma unroll
  for (int qi = 0; qi < 2; ++qi)
    #pragma unroll
    for (int kh = 0; kh < 2; ++kh)
      qf[qi][kh] = *(const s16x8_a*)(Q + (size_t)(q0 + qi * 16 + c) * 64 + kh * 32 + g * 8);

  // constant ones-column B-fragment: l = P . 1 on the MFMA pipe
  s16x8 onesf;
  {
    const short one = (short)0x3F80, val = (c == 0) ? one : (short)0;
    #pragma unroll
    for (int j = 0; j < 8; ++j) onesf[j] = val;
  }

  f32x4 o[2][4] = {};
  f32x4 o_l[2] = {};
  const f32x4 kZero = {0.f, 0.f, 0.f, 0.f};

  // --- DMA lane mappings (4 waves -> 2 calls per tile), XOR-swizzled LDS ---
  const int keyK = w * 16 + (lane >> 2);
  const int ccK = (lane & 3) ^ ((keyK >> 1) & 3);
  const USH* gK0 = K + (size_t)keyK * 64 + ccK * 8;   // +kt*4096 +j*32
  const int hdV = w * 8 + (lane >> 3);
  const int ccV = (lane & 7) ^ (hdV & 7);
  const USH* gV0 = V + (size_t)hdV * 4096 + ccV * 8;  // +kt*64 +j*32*4096
  USH* lK = Ks + w * 512 + lane * 8;   // +kbuf +j*2048
  USH* lV = Vt + w * 512 + lane * 8;   // +vslot +j*2048

  // issue K/V tile `kt` DMA into LDS offsets kOff (K) / vOff (V)
  auto DMA = [&](int kt, int kOff, int vOff) {
    #pragma unroll
    for (int j = 0; j < 2; ++j) {
      gld_lds16(gK0 + (size_t)kt * 4096 + j * 32, lK + kOff + j * 2048);
      gld_lds16(gV0 + (size_t)kt * 64 + (size_t)j * 131072, lV + vOff + j * 2048);
    }
  };

  // S^T[key][qrow] = K * Q^T into st (overwrites; Q pre-scaled by sc*log2e)
  auto QK = [&](int kbase, f32x4 (&st)[2][4]) {
    s16x8 ak[4];
    #pragma unroll
    for (int kff = 0; kff < 4; ++kff) {
      const int row = kff * 16 + c;
      const int qsw = (g ^ ((c >> 1) & 3)) * 8;
      ak[kff] = *(const s16x8_a*)(Ks + kbase + row * 32 + qsw);
    }
    #pragma unroll
    for (int qi = 0; qi < 2; ++qi)
      #pragma unroll
      for (int kff = 0; kff < 4; ++kff)
        st[qi][kff] = mfma16(ak[kff], qf[qi][0], kZero);
    #pragma unroll
    for (int kff = 0; kff < 4; ++kff) {
      const int row = kff * 16 + c;
      const int qsw = (g ^ ((c >> 1) & 3)) * 8;
      ak[kff] = *(const s16x8_a*)(Ks + kbase + 2048 + row * 32 + qsw);
    }
    #pragma unroll
    for (int qi = 0; qi < 2; ++qi)
      #pragma unroll
      for (int kff = 0; kff < 4; ++kff)
        st[qi][kff] = mfma16(ak[kff], qf[qi][1], st[qi][kff]);
  };

  // softmax (exp2) + pack P + PV accumulate for a PREVIOUS tile's st.
  auto SMPV = [&](f32x4 (&st)[2][4], int vbase) {
    #pragma unroll
    for (int qi = 0; qi < 2; ++qi)
      #pragma unroll
      for (int kff = 0; kff < 4; ++kff) {
        #pragma unroll
        for (int r = 0; r < 4; ++r) st[qi][kff][r] = EXP2F(st[qi][kff][r]);
        const unsigned int lo = pk_bf16(st[qi][kff][0], st[qi][kff][1]);
        const unsigned int hi = pk_bf16(st[qi][kff][2], st[qi][kff][3]);
        *(u64_a*)(&Ps[w][(qi * 16 + c) * 76 + kff * 16 + g * 4]) =
            (unsigned long long)lo | ((unsigned long long)hi << 32);
      }
    #pragma unroll
    for (int kf = 0; kf < 2; ++kf) {
      s16x8 ap[2];
      #pragma unroll
      for (int qi = 0; qi < 2; ++qi)
        ap[qi] = *(const s16x8_a*)(&Ps[w][(qi * 16 + c) * 76 + kf * 32 + g * 8]);
      s16x8 bv[4];
      #pragma unroll
      for (int hf = 0; hf < 4; ++hf) {
        const int qv = ((kf * 4 + g) ^ (c & 7)) * 8;
        bv[hf] = *(const s16x8_a*)(Vt + vbase + (c + 16 * hf) * 64 + qv);
      }
      #pragma unroll
      for (int qi = 0; qi < 2; ++qi) {
        #pragma unroll
        for (int hf = 0; hf < 4; ++hf)
          o[qi][hf] = mfma16(ap[qi], bv[hf], o[qi][hf]);
        o_l[qi] = mfma16(ap[qi], onesf, o_l[qi]);
      }
    }
  };

  f32x4 stA[2][4], stB[2][4];

  // prologue: tile0 -> Kbuf0/Vslot0; tile1 -> Kbuf1/Vslot1; QK(0)
  DMA(0, 0, 0);
  __syncthreads();           // tile0 resident
  DMA(1, 4096, 4096);
  QK(0, stA);
  int vD = 8192;             // DMA(kt+1) V slot: tile2 -> slot 2
  int vP = 0;                // PV(kt-1) V slot: tile0 -> slot 0

  for (int j = 0; j < 31; ++j) {
    // half A: kt = 2j+1 (K in buf1); DMA tile kt+1 (even) -> Kbuf0
    __syncthreads();         // tile kt resident; Kbuf0 / V slot vD free
    DMA(2 * j + 2, 0, vD);
    QK(4096, stB);
    SMPV(stA, vP);
    vD = (vD == 8192) ? 0 : vD + 4096;
    vP = (vP == 8192) ? 0 : vP + 4096;
    // half B: kt = 2j+2 (K in buf0); DMA tile kt+1 (odd) -> Kbuf1
    __syncthreads();
    DMA(2 * j + 3, 4096, vD);
    QK(0, stA);
    SMPV(stB, vP);
    vD = (vD == 8192) ? 0 : vD + 4096;
    vP = (vP == 8192) ? 0 : vP + 4096;
  }
  // tail: kt=63 (K in buf1, V already resident); then drain PV(63)
  __syncthreads();
  QK(4096, stB);
  SMPV(stA, vP);             // PV(62)
  vP = (vP == 8192) ? 0 : vP + 4096;
  SMPV(stB, vP);             // PV(63): Ps wave-local in-order; V slot resident

  // l lives in lanes c==0 (D[m][0]); broadcast within the wave via LDS
  if (c == 0) {
    #pragma unroll
    for (int qi = 0; qi < 2; ++qi)
      #pragma unroll
      for (int r = 0; r < 4; ++r) lbuf[w][qi * 16 + g * 4 + r] = o_l[qi][r];
  }
  __syncthreads();

  #pragma unroll
  for (int qi = 0; qi < 2; ++qi)
    #pragma unroll
    for (int r = 0; r < 4; ++r) {
      const int ml = qi * 16 + g * 4 + r;
      const float linv = 1.0f / lbuf[w][ml];
      const int qrow = q0 + ml;
      #pragma unroll
      for (int hf = 0; hf < 4; ++hf) {
        const int hd = c + 16 * hf;
        att[((size_t)(bb * 4096 + qrow)) * 512 + hh * 64 + hd] =
            f2bf(o[qi][hf][r] * linv);
      }
    }
}

extern "C" void kernel_launch(void* const* d_in, const int* in_sizes, int n_in,
                              void* d_out, int out_size, void* d_ws, size_t ws_size,
                              hipStream_t stream) {
  (void)in_sizes; (void)n_in; (void)out_size; (void)ws_size;
  const float* x  = (const float*)d_in[0];
  const float* Wq = (const float*)d_in[1];
  const float* bq = (const float*)d_in[2];
  const float* Wk = (const float*)d_in[3];
  const float* bk = (const float*)d_in[4];
  const float* Wv = (const float*)d_in[5];
  const float* bv = (const float*)d_in[6];
  const float* Wo = (const float*)d_in[7];
  const float* bo = (const float*)d_in[8];
  USH* ws  = (USH*)d_ws;
  USH* wT  = ws;                       // 4 * 262144 bf16 transposed weights (2 MB)
  USH* kv  = ws + 1048576;             // K [B,H,S,Hd] + V [B,H,Hd,S] bf16 (16 MB)
  USH* att = ws + 1048576 + 8388608;   // 4194304 : attn out [B,S,D] bf16 (8 MB)
  float* outF = (float*)d_out;         // fp32 output (16 MB)
  USH* qscratch = (USH*)d_out;         // Q bf16 (8 MB), dead before final GEMM
  USH* xb = (USH*)d_out + 4194304;     // x bf16 (8 MB), dead before final GEMM

  prep<<<dim3(16, 16, 5), 256, 0, stream>>>(Wq, Wk, Wv, Wo, x, wT, xb);
  gemm_bias<1><<<dim3(64, 4, 3), 256, 0, stream>>>(xb, wT, bq, bk, bv,
                                                   qscratch, kv, nullptr);
  attn<<<dim3(32, 16), 256, 0, stream>>>(qscratch, kv, att);
  gemm_bias<0><<<dim3(64, 4, 1), 256, 0, stream>>>(att, wT + 3 * 262144, bo, bo, bo,
                                                   nullptr, nullptr, outF);
}

// Round 4
// 210.686 us; speedup vs baseline: 1.0183x; 1.0183x over previous
//
#include <hip/hip_runtime.h>

typedef unsigned short USH;
typedef short s16x8 __attribute__((ext_vector_type(8)));
typedef float f32x4 __attribute__((ext_vector_type(4)));
typedef float f32x4v __attribute__((ext_vector_type(4)));
typedef unsigned int u32x4 __attribute__((ext_vector_type(4)));
// may_alias variants for ALL type-punned LDS/global accesses.
typedef s16x8 s16x8_a __attribute__((may_alias));
typedef f32x4v f32x4v_a __attribute__((may_alias));
typedef u32x4 u32x4_a __attribute__((may_alias));
typedef unsigned long long u64_a __attribute__((may_alias));

#if __has_builtin(__builtin_amdgcn_exp2f)
#define EXP2F(x) __builtin_amdgcn_exp2f(x)  // raw v_exp_f32, no legalization
#else
#define EXP2F(x) __builtin_exp2f(x)
#endif

__device__ __forceinline__ USH f2bf(float f) {
  union { float f; unsigned int i; } c; c.f = f;
  unsigned int x = c.i;
  return (USH)((x + 0x7FFFu + ((x >> 16) & 1u)) >> 16);
}
__device__ __forceinline__ unsigned int pk_bf16(float a, float b) {
#if __has_builtin(__builtin_amdgcn_cvt_pk_bf16_f32)
  typedef USH ush2 __attribute__((ext_vector_type(2)));
  union { ush2 v; unsigned int u; } r;
  r.v = __builtin_amdgcn_cvt_pk_bf16_f32(a, b);
  return r.u;
#else
  union { float f; unsigned int i; } ca, cb; ca.f = a; cb.f = b;
  return ((ca.i + 0x8000u) >> 16) | ((cb.i + 0x8000u) & 0xFFFF0000u);
#endif
}

__device__ __forceinline__ f32x4 mfma16(s16x8 a, s16x8 b, f32x4 c) {
  return __builtin_amdgcn_mfma_f32_16x16x32_bf16(a, b, c, 0, 0, 0);
}

// async global->LDS, 16B per lane; LDS dest semantics: wave base + lane*16.
#if __has_builtin(__builtin_amdgcn_global_load_lds)
__device__ __forceinline__ void gld_lds16(const USH* g, USH* l) {
  __builtin_amdgcn_global_load_lds(
      static_cast<const unsigned int __attribute__((address_space(1)))*>(
          (const void __attribute__((address_space(1)))*)g),
      static_cast<unsigned int __attribute__((address_space(3)))*>(
          (void __attribute__((address_space(3)))*)l),
      16, 0, 0);
}
#else
__device__ __forceinline__ void gld_lds16(const USH* g, USH* l) {
  *(s16x8_a*)l = *(const s16x8_a*)g;  // fallback: synchronous copy, same addresses
}
#endif

// ------------- prep: z<4 -> WT[n][k] = bf16(W[k][n]);  z==4 -> xb = bf16(x) -------------
__global__ __launch_bounds__(256) void prep(
    const float* __restrict__ Wq, const float* __restrict__ Wk,
    const float* __restrict__ Wv, const float* __restrict__ Wo,
    const float* __restrict__ x, USH* __restrict__ wsT, USH* __restrict__ xb) {
  __shared__ float tile[32][33];
  const int z = blockIdx.z;
  const int t = threadIdx.x;
  if (z == 4) {  // convert x: 256 blocks x 16384 floats
    const size_t b0 = ((size_t)blockIdx.y * 16 + blockIdx.x) * 16384;
    #pragma unroll
    for (int j = 0; j < 8; ++j) {
      const size_t i = b0 + (size_t)j * 2048 + t * 8;
      const f32x4v a = *(const f32x4v_a*)(x + i);
      const f32x4v b = *(const f32x4v_a*)(x + i + 4);
      u32x4 s;
      s.x = pk_bf16(a.x, a.y); s.y = pk_bf16(a.z, a.w);
      s.z = pk_bf16(b.x, b.y); s.w = pk_bf16(b.z, b.w);
      *(u32x4_a*)(xb + i) = s;
    }
    return;
  }
  const float* W = (z == 0) ? Wq : (z == 1) ? Wk : (z == 2) ? Wv : Wo;
  USH* WT = wsT + (size_t)z * 262144;
  const int n0 = blockIdx.x * 32, k0 = blockIdx.y * 32;
  const int tx = t & 31, ty = t >> 5;  // 32 x 8
  #pragma unroll
  for (int i = 0; i < 4; ++i)
    tile[ty + i * 8][tx] = W[(size_t)(k0 + ty + i * 8) * 512 + n0 + tx];
  __syncthreads();
  #pragma unroll
  for (int i = 0; i < 4; ++i)
    WT[(size_t)(n0 + ty + i * 8) * 512 + k0 + tx] = f2bf(tile[tx][ty + i * 8]);
}

// ---------------- GEMM: out = A[M,512](bf16) * WT^T + bias ----------------
// ROUND-13 PROVEN VERSION (round-14 operand-swap epilogue regressed −43us:
// per-lane b64/f32x4 stores put consecutive lanes 128B..2KB apart -> 16 cache
// lines per store inst vs 4 for the scalar-consecutive epilogue. Reverted.)
// MODE 0: float out[m*512+n] (d_out fp32).
// MODE 1: z==0 -> Q bf16 [B,H,S,Hd] scaled by sc*log2e; z==1 -> K [B,H,S,Hd];
//         z==2 -> V [B,H,Hd,S] (pre-transposed for attn).
// BK=64, register prefetch, 3 blocks/CU (768-block QKV dispatch single-pass).
template <int MODE>
__global__ __launch_bounds__(256, 3) void gemm_bias(
    const USH* __restrict__ A, const USH* __restrict__ BT0,
    const float* __restrict__ b0, const float* __restrict__ b1,
    const float* __restrict__ b2,
    USH* __restrict__ oQ, USH* __restrict__ oKV, float* __restrict__ oF) {
  __shared__ __align__(16) USH As[128 * 68];
  __shared__ __align__(16) USH Bs[128 * 68];
  const int z = blockIdx.z;
  const USH* BT = BT0 + (size_t)z * 262144;
  const float* bias = (z == 0) ? b0 : ((z == 1) ? b1 : b2);
  USH* outb = (z == 0) ? oQ : (oKV + (size_t)(z - 1) * 4194304);
  const float qs = (MODE == 1 && z == 0) ? 0.06375871528132839f : 1.0f;

  const int t = threadIdx.x;
  const int w = t >> 6, lane = t & 63;
  const int c = lane & 15, g = lane >> 4;
  const int wm = w & 1, wn = w >> 1;
  const int m0 = blockIdx.x * 128, n0 = blockIdx.y * 128;
  const int srow = t >> 1, scol = (t & 1) * 32;

  f32x4 acc[4][4] = {};

  const USH* Ap0 = A + (size_t)(m0 + srow) * 512 + scol;
  const USH* Bp0 = BT + (size_t)(n0 + srow) * 512 + scol;
  s16x8 pa[4], pb[4];
  #pragma unroll
  for (int j = 0; j < 4; ++j) {
    pa[j] = *(const s16x8_a*)(Ap0 + j * 8);
    pb[j] = *(const s16x8_a*)(Bp0 + j * 8);
  }

  for (int kt = 0; kt < 8; ++kt) {
    __syncthreads();
    #pragma unroll
    for (int j = 0; j < 4; ++j) {
      *(s16x8_a*)(As + srow * 68 + scol + j * 8) = pa[j];
      *(s16x8_a*)(Bs + srow * 68 + scol + j * 8) = pb[j];
    }
    const int ktn = (kt < 7) ? kt + 1 : kt;
    #pragma unroll
    for (int j = 0; j < 4; ++j) {
      pa[j] = *(const s16x8_a*)(Ap0 + ktn * 64 + j * 8);
      pb[j] = *(const s16x8_a*)(Bp0 + ktn * 64 + j * 8);
    }
    __syncthreads();
    #pragma unroll
    for (int ks = 0; ks < 2; ++ks) {
      s16x8 af[4], bfr[4];
      #pragma unroll
      for (int i = 0; i < 4; ++i) {
        af[i]  = *(const s16x8_a*)(As + (wm * 64 + i * 16 + c) * 68 + ks * 32 + g * 8);
        bfr[i] = *(const s16x8_a*)(Bs + (wn * 64 + i * 16 + c) * 68 + ks * 32 + g * 8);
      }
      #pragma unroll
      for (int mf = 0; mf < 4; ++mf)
        #pragma unroll
        for (int nf = 0; nf < 4; ++nf)
          acc[mf][nf] = mfma16(af[mf], bfr[nf], acc[mf][nf]);
    }
  }

  #pragma unroll
  for (int nf = 0; nf < 4; ++nf) {
    const int n = n0 + wn * 64 + nf * 16 + c;
    const float bv = bias[n];
    #pragma unroll
    for (int mf = 0; mf < 4; ++mf)
      #pragma unroll
      for (int r = 0; r < 4; ++r) {
        const int m = m0 + wm * 64 + mf * 16 + g * 4 + r;
        const float v = (acc[mf][nf][r] + bv) * qs;
        if (MODE == 0) {
          oF[(size_t)m * 512 + n] = v;
        } else {
          const int bb = m >> 12, s = m & 4095, h = n >> 6, hd = n & 63;
          if (z == 2)
            outb[(((size_t)(bb * 8 + h)) * 64 + hd) * 4096 + s] = f2bf(v);
          else
            outb[(((size_t)(bb * 8 + h)) * 4096 + s) * 64 + hd] = f2bf(v);
        }
      }
  }
}

// ---------------- flash attention v13: counted-vmcnt pipeline (no drain) ----------------
// v9-v12 post-mortem: per-iter time ~3900 cyc invariant to memory level (r0),
// LDS traffic -36% (r1), waves/SIMD 4->2 (r1), intra-wave phase order (r2).
// Every throughput model contradicts at least one of those nulls; the serial
// chain of one iteration is only ~800 cyc. The untouched invariant: depth-1
// DMA prefetch + full vmcnt(0) drain at every __syncthreads -- the DMA
// issue->L2->LDS->drain round-trip re-serializes into EVERY iteration, and
// no compute restructuring hides it (== learn_hip m233: stage+vmcnt+barrier
// = 72% of 2-phase GEMM; removing other pieces alone doesn't help; m218:
// counted vmcnt vs drain-0 = +38..73%).
// v13 = v11 with: 3-slot K/V rings, depth-2 prefetch, ONE fused
// "s_waitcnt vmcnt(N); s_barrier" (raw asm, memory clobber, NO lgkm/vm drain)
// per iteration. Steady state: 8 loads in flight/wave, wait vmcnt(4) -> tile
// kt's loads done; tile kt+2's DMA spans two full iterations. Safe without
// lgkm drain: Ps is wave-local (in-order DS), K/V written only by DMA
// (vmcnt-tracked), lbuf guarded by full __syncthreads in epilogue.
// Slot (kt+2)%3 is freed exactly at barrier kt (last reader was iter kt-1).
// LDS: K 24K + V 24K + Ps 19K + lbuf 0.5K = 69.1 KB -> 2 blocks/CU.
// Q pre-scaled by sc*log2e -> p = exp2(s). l = P.1 on the MFMA pipe.
__global__ __launch_bounds__(256, 2) void attn(const USH* __restrict__ Qbuf,
                                               const USH* __restrict__ kv,
                                               USH* __restrict__ att) {
  __shared__ __align__(16) USH Ks[3 * 4096];   // K tile kt in slot kt%3
  __shared__ __align__(16) USH Vt[3 * 4096];   // V tile kt in slot kt%3
  __shared__ __align__(16) USH Ps[4][32 * 76]; // per-wave [32 qrow][76 key-pad]
  __shared__ float lbuf[4][32];

  const int t = threadIdx.x;
  const int w = t >> 6, lane = t & 63;
  const int c = lane & 15, g = lane >> 4;
  // XCD-aware remap: each XCD owns 2 bh -> KV working set 2 MB <= L2 (kept
  // from v10: halves HBM fetch; shortens DMA latency).
  const int linear = blockIdx.x + (blockIdx.y << 5);
  const int xcd = linear & 7, idx = linear >> 3;
  const int bh = xcd + ((idx >> 5) << 3);
  const int bb = bh >> 3, hh = bh & 7;
  const size_t base = (size_t)bh * 262144;  // 4096*64
  const USH* Q = Qbuf + base;
  const USH* K = kv + base;                 // [S,Hd]
  const USH* V = kv + 4194304 + base;       // [Hd,S] (pre-transposed)
  const int q0 = (idx & 31) * 128 + w * 32;

  // Q fragments (B-operand of S^T): registers for the whole K loop
  s16x8 qf[2][2];  // [qi][kh]
  #pragma unroll
  for (int qi = 0; qi < 2; ++qi)
    #pragma unroll
    for (int kh = 0; kh < 2; ++kh)
      qf[qi][kh] = *(const s16x8_a*)(Q + (size_t)(q0 + qi * 16 + c) * 64 + kh * 32 + g * 8);

  // constant ones-column B-fragment: l = P . 1 on the MFMA pipe
  s16x8 onesf;
  {
    const short one = (short)0x3F80, val = (c == 0) ? one : (short)0;
    #pragma unroll
    for (int j = 0; j < 8; ++j) onesf[j] = val;
  }

  f32x4 o[2][4] = {};
  f32x4 o_l[2] = {};

  // --- DMA lane mappings (4 waves -> 2 calls per tile), XOR-swizzled LDS ---
  const int keyK = w * 16 + (lane >> 2);
  const int ccK = (lane & 3) ^ ((keyK >> 1) & 3);
  const USH* gK0 = K + (size_t)keyK * 64 + ccK * 8;   // +kt*4096 +j*32
  const int hdV = w * 8 + (lane >> 3);
  const int ccV = (lane & 7) ^ (hdV & 7);
  const USH* gV0 = V + (size_t)hdV * 4096 + ccV * 8;  // +kt*64 +j*32*4096
  USH* lK = Ks + w * 512 + lane * 8;   // +slot +j*2048
  USH* lV = Vt + w * 512 + lane * 8;   // +slot +j*2048

  // issue K/V tile `kt` DMA into LDS slot offset `slotOff` (USH units)
  auto DMA = [&](int kt, int slotOff) {
    #pragma unroll
    for (int j = 0; j < 2; ++j) {
      gld_lds16(gK0 + (size_t)kt * 4096 + j * 32, lK + slotOff + j * 2048);
      gld_lds16(gV0 + (size_t)kt * 64 + (size_t)j * 131072, lV + slotOff + j * 2048);
    }
  };

  // QK + exp2 + pack P + PV for the tile resident in slot `sb` (USH offset)
  auto STEP = [&](int sb) {
    // S^T[key][qrow] = K * Q^T  (Q pre-scaled; st IS the exp2 argument)
    f32x4 st[2][4] = {};
    #pragma unroll
    for (int kh = 0; kh < 2; ++kh) {
      s16x8 ak[4];
      #pragma unroll
      for (int kff = 0; kff < 4; ++kff) {
        const int row = kff * 16 + c;
        const int qsw = (g ^ ((c >> 1) & 3)) * 8;
        ak[kff] = *(const s16x8_a*)(Ks + sb + kh * 2048 + row * 32 + qsw);
      }
      #pragma unroll
      for (int qi = 0; qi < 2; ++qi)
        #pragma unroll
        for (int kff = 0; kff < 4; ++kff)
          st[qi][kff] = mfma16(ak[kff], qf[qi][kh], st[qi][kff]);
    }
    // p = exp2(s); pack; write P to Ps[w] (wave-local; in-order DS)
    #pragma unroll
    for (int qi = 0; qi < 2; ++qi)
      #pragma unroll
      for (int kff = 0; kff < 4; ++kff) {
        #pragma unroll
        for (int r = 0; r < 4; ++r) st[qi][kff][r] = EXP2F(st[qi][kff][r]);
        const unsigned int lo = pk_bf16(st[qi][kff][0], st[qi][kff][1]);
        const unsigned int hi = pk_bf16(st[qi][kff][2], st[qi][kff][3]);
        *(u64_a*)(&Ps[w][(qi * 16 + c) * 76 + kff * 16 + g * 4]) =
            (unsigned long long)lo | ((unsigned long long)hi << 32);
      }
    // O[qrow][hd] += P * V ; l[qrow] += P . 1
    #pragma unroll
    for (int kf = 0; kf < 2; ++kf) {
      s16x8 ap[2];
      #pragma unroll
      for (int qi = 0; qi < 2; ++qi)
        ap[qi] = *(const s16x8_a*)(&Ps[w][(qi * 16 + c) * 76 + kf * 32 + g * 8]);
      s16x8 bv[4];
      #pragma unroll
      for (int hf = 0; hf < 4; ++hf) {
        const int qv = ((kf * 4 + g) ^ (c & 7)) * 8;
        bv[hf] = *(const s16x8_a*)(Vt + sb + (c + 16 * hf) * 64 + qv);
      }
      #pragma unroll
      for (int qi = 0; qi < 2; ++qi) {
        #pragma unroll
        for (int hf = 0; hf < 4; ++hf)
          o[qi][hf] = mfma16(ap[qi], bv[hf], o[qi][hf]);
        o_l[qi] = mfma16(ap[qi], onesf, o_l[qi]);
      }
    }
  };

  // prologue: depth-2 prefetch (8 loads in flight per wave)
  DMA(0, 0);
  DMA(1, 4096);
  int sCur = 0, sNext = 4096, sFree = 8192;

  for (int kt = 0; kt < 62; ++kt) {
    // wait own tile-kt loads (leave tile kt+1's 4 in flight), then barrier:
    // tile kt resident block-wide AND slot sFree free (last read was kt-1).
    asm volatile("s_waitcnt vmcnt(4)\n\ts_barrier" ::: "memory");
    DMA(kt + 2, sFree);
    STEP(sCur);
    const int tmp = sCur; sCur = sNext; sNext = sFree; sFree = tmp;
  }
  // kt = 62: tile 63 still in flight (4 outstanding)
  asm volatile("s_waitcnt vmcnt(4)\n\ts_barrier" ::: "memory");
  STEP(sCur);
  { const int tmp = sCur; sCur = sNext; sNext = sFree; sFree = tmp; }
  // kt = 63: drain the last tile
  asm volatile("s_waitcnt vmcnt(0)\n\ts_barrier" ::: "memory");
  STEP(sCur);

  // l lives in lanes c==0 (D[m][0]); broadcast within the wave via LDS
  if (c == 0) {
    #pragma unroll
    for (int qi = 0; qi < 2; ++qi)
      #pragma unroll
      for (int r = 0; r < 4; ++r) lbuf[w][qi * 16 + g * 4 + r] = o_l[qi][r];
  }
  __syncthreads();

  #pragma unroll
  for (int qi = 0; qi < 2; ++qi)
    #pragma unroll
    for (int r = 0; r < 4; ++r) {
      const int ml = qi * 16 + g * 4 + r;
      const float linv = 1.0f / lbuf[w][ml];
      const int qrow = q0 + ml;
      #pragma unroll
      for (int hf = 0; hf < 4; ++hf) {
        const int hd = c + 16 * hf;
        att[((size_t)(bb * 4096 + qrow)) * 512 + hh * 64 + hd] =
            f2bf(o[qi][hf][r] * linv);
      }
    }
}

extern "C" void kernel_launch(void* const* d_in, const int* in_sizes, int n_in,
                              void* d_out, int out_size, void* d_ws, size_t ws_size,
                              hipStream_t stream) {
  (void)in_sizes; (void)n_in; (void)out_size; (void)ws_size;
  const float* x  = (const float*)d_in[0];
  const float* Wq = (const float*)d_in[1];
  const float* bq = (const float*)d_in[2];
  const float* Wk = (const float*)d_in[3];
  const float* bk = (const float*)d_in[4];
  const float* Wv = (const float*)d_in[5];
  const float* bv = (const float*)d_in[6];
  const float* Wo = (const float*)d_in[7];
  const float* bo = (const float*)d_in[8];
  USH* ws  = (USH*)d_ws;
  USH* wT  = ws;                       // 4 * 262144 bf16 transposed weights (2 MB)
  USH* kv  = ws + 1048576;             // K [B,H,S,Hd] + V [B,H,Hd,S] bf16 (16 MB)
  USH* att = ws + 1048576 + 8388608;   // 4194304 : attn out [B,S,D] bf16 (8 MB)
  float* outF = (float*)d_out;         // fp32 output (16 MB)
  USH* qscratch = (USH*)d_out;         // Q bf16 (8 MB), dead before final GEMM
  USH* xb = (USH*)d_out + 4194304;     // x bf16 (8 MB), dead before final GEMM

  prep<<<dim3(16, 16, 5), 256, 0, stream>>>(Wq, Wk, Wv, Wo, x, wT, xb);
  gemm_bias<1><<<dim3(64, 4, 3), 256, 0, stream>>>(xb, wT, bq, bk, bv,
                                                   qscratch, kv, nullptr);
  attn<<<dim3(32, 16), 256, 0, stream>>>(qscratch, kv, att);
  gemm_bias<0><<<dim3(64, 4, 1), 256, 0, stream>>>(att, wT + 3 * 262144, bo, bo, bo,
                                                   nullptr, nullptr, outF);
}

// Round 6
// 209.963 us; speedup vs baseline: 1.0218x; 1.0034x over previous
//
#include <hip/hip_runtime.h>

typedef unsigned short USH;
typedef short s16x8 __attribute__((ext_vector_type(8)));
typedef float f32x4 __attribute__((ext_vector_type(4)));
typedef float f32x4v __attribute__((ext_vector_type(4)));
typedef unsigned int u32x4 __attribute__((ext_vector_type(4)));
// may_alias variants for ALL type-punned LDS/global accesses.
typedef s16x8 s16x8_a __attribute__((may_alias));
typedef f32x4v f32x4v_a __attribute__((may_alias));
typedef u32x4 u32x4_a __attribute__((may_alias));
typedef unsigned long long u64_a __attribute__((may_alias));

#if __has_builtin(__builtin_amdgcn_exp2f)
#define EXP2F(x) __builtin_amdgcn_exp2f(x)  // raw v_exp_f32, no legalization
#else
#define EXP2F(x) __builtin_exp2f(x)
#endif

__device__ __forceinline__ USH f2bf(float f) {
  union { float f; unsigned int i; } c; c.f = f;
  unsigned int x = c.i;
  return (USH)((x + 0x7FFFu + ((x >> 16) & 1u)) >> 16);
}
__device__ __forceinline__ unsigned int pk_bf16(float a, float b) {
#if __has_builtin(__builtin_amdgcn_cvt_pk_bf16_f32)
  typedef USH ush2 __attribute__((ext_vector_type(2)));
  union { ush2 v; unsigned int u; } r;
  r.v = __builtin_amdgcn_cvt_pk_bf16_f32(a, b);
  return r.u;
#else
  union { float f; unsigned int i; } ca, cb; ca.f = a; cb.f = b;
  return ((ca.i + 0x8000u) >> 16) | ((cb.i + 0x8000u) & 0xFFFF0000u);
#endif
}

__device__ __forceinline__ f32x4 mfma16(s16x8 a, s16x8 b, f32x4 c) {
  return __builtin_amdgcn_mfma_f32_16x16x32_bf16(a, b, c, 0, 0, 0);
}

// async global->LDS, 16B per lane; LDS dest semantics: wave base + lane*16.
#if __has_builtin(__builtin_amdgcn_global_load_lds)
__device__ __forceinline__ void gld_lds16(const USH* g, USH* l) {
  __builtin_amdgcn_global_load_lds(
      static_cast<const unsigned int __attribute__((address_space(1)))*>(
          (const void __attribute__((address_space(1)))*)g),
      static_cast<unsigned int __attribute__((address_space(3)))*>(
          (void __attribute__((address_space(3)))*)l),
      16, 0, 0);
}
#else
__device__ __forceinline__ void gld_lds16(const USH* g, USH* l) {
  *(s16x8_a*)l = *(const s16x8_a*)g;  // fallback: synchronous copy, same addresses
}
#endif

// ------------- prep: z<4 -> WT[n][k] = bf16(W[k][n]);  z==4 -> xb = bf16(x) -------------
__global__ __launch_bounds__(256) void prep(
    const float* __restrict__ Wq, const float* __restrict__ Wk,
    const float* __restrict__ Wv, const float* __restrict__ Wo,
    const float* __restrict__ x, USH* __restrict__ wsT, USH* __restrict__ xb) {
  __shared__ float tile[32][33];
  const int z = blockIdx.z;
  const int t = threadIdx.x;
  if (z == 4) {  // convert x: 256 blocks x 16384 floats
    const size_t b0 = ((size_t)blockIdx.y * 16 + blockIdx.x) * 16384;
    #pragma unroll
    for (int j = 0; j < 8; ++j) {
      const size_t i = b0 + (size_t)j * 2048 + t * 8;
      const f32x4v a = *(const f32x4v_a*)(x + i);
      const f32x4v b = *(const f32x4v_a*)(x + i + 4);
      u32x4 s;
      s.x = pk_bf16(a.x, a.y); s.y = pk_bf16(a.z, a.w);
      s.z = pk_bf16(b.x, b.y); s.w = pk_bf16(b.z, b.w);
      *(u32x4_a*)(xb + i) = s;
    }
    return;
  }
  const float* W = (z == 0) ? Wq : (z == 1) ? Wk : (z == 2) ? Wv : Wo;
  USH* WT = wsT + (size_t)z * 262144;
  const int n0 = blockIdx.x * 32, k0 = blockIdx.y * 32;
  const int tx = t & 31, ty = t >> 5;  // 32 x 8
  #pragma unroll
  for (int i = 0; i < 4; ++i)
    tile[ty + i * 8][tx] = W[(size_t)(k0 + ty + i * 8) * 512 + n0 + tx];
  __syncthreads();
  #pragma unroll
  for (int i = 0; i < 4; ++i)
    WT[(size_t)(n0 + ty + i * 8) * 512 + k0 + tx] = f2bf(tile[tx][ty + i * 8]);
}

// ---------------- GEMM v3: out = A[M,512](bf16) * WT^T + bias ----------------
// Round-5 post-mortem: the counted-vmcnt ring (v2) tripped the determinism
// tripwire -- launch_once vs graph replay diverged (race; suspect: LLVM may
// not order the global_load_lds intrinsic against inline-asm "memory"
// barriers). REVERTED to __syncthreads-only (compiler emits full
// vmcnt(0)+lgkmcnt(0) drain before s_barrier -> every cross-wave LDS hazard
// fenced -> deterministic by construction).
// Kept improvement vs the reg-staged baseline: m97-proven single-buffer
// 2-barrier structure with global_load_lds staging (no VGPR round-trip, no
// ds_write, far less VALU). BK=64, 32 KB LDS, 3 blocks/CU (768-block QKV
// dispatch still fits in one residency round). Latency hidden by cross-block
// overlap (per-block barriers desynchronize the 3 blocks/CU).
// XOR-swizzle both-sides (rule #21): row r has 8x16B chunks; phys chunk p
// holds global chunk p^(r&7) (DMA source pre-swizzled); ds_read reads phys
// chunk (ks*4+g)^(r&7) -> global chunk ks*4+g. Read pattern: 16 lanes hit 8
// distinct chunk-columns x 2 rows = 2-way = free (m136).
// MODE 0: float out[m*512+n] (d_out fp32).
// MODE 1: z==0 -> Q bf16 [B,H,S,Hd] scaled by sc*log2e; z==1 -> K [B,H,S,Hd];
//         z==2 -> V [B,H,Hd,S] (pre-transposed for attn).
template <int MODE>
__global__ __launch_bounds__(256, 3) void gemm_bias(
    const USH* __restrict__ A, const USH* __restrict__ BT0,
    const float* __restrict__ b0, const float* __restrict__ b1,
    const float* __restrict__ b2,
    USH* __restrict__ oQ, USH* __restrict__ oKV, float* __restrict__ oF) {
  __shared__ __align__(16) USH As[8192];  // [128 rows][64 USH] chunk-swizzled
  __shared__ __align__(16) USH Bs[8192];
  const int z = blockIdx.z;
  const USH* BT = BT0 + (size_t)z * 262144;
  const float* bias = (z == 0) ? b0 : ((z == 1) ? b1 : b2);
  USH* outb = (z == 0) ? oQ : (oKV + (size_t)(z - 1) * 4194304);
  const float qs = (MODE == 1 && z == 0) ? 0.06375871528132839f : 1.0f;

  const int t = threadIdx.x;
  const int w = t >> 6, lane = t & 63;
  const int c = lane & 15, g = lane >> 4;
  const int wm = w & 1, wn = w >> 1;
  const int m0 = blockIdx.x * 128, n0 = blockIdx.y * 128;

  f32x4 acc[4][4] = {};

  // --- DMA mapping: instruction j of wave w covers rows w*32 + j*8 + (lane>>3),
  // phys chunk lane&7 (dest = base + lane*16B, linear). Source pre-swizzled:
  // global chunk (lane&7)^(row&7), row&7 == (lane>>3)&7 for all j,w.
  const int rD = w * 32 + (lane >> 3);                       // +j*8
  const int ccD = (((lane & 7) ^ ((lane >> 3) & 7))) * 8;    // global chunk*8
  const USH* ApD = A + (size_t)(m0 + rD) * 512 + ccD;        // +kt*64 +j*4096
  const USH* BpD = BT + (size_t)(n0 + rD) * 512 + ccD;
  USH* lA = As + w * 2048 + lane * 8;                        // +j*512
  USH* lB = Bs + w * 2048 + lane * 8;

  for (int kt = 0; kt < 8; ++kt) {
    __syncthreads();  // full drain: previous COMPUTE's ds_reads done -> safe to overwrite
    #pragma unroll
    for (int j = 0; j < 4; ++j) {
      gld_lds16(ApD + kt * 64 + j * 4096, lA + j * 512);
      gld_lds16(BpD + kt * 64 + j * 4096, lB + j * 512);
    }
    __syncthreads();  // full drain: DMA landed -> tile kt resident block-wide
    #pragma unroll
    for (int ks = 0; ks < 2; ++ks) {
      s16x8 af[4], bfr[4];
      #pragma unroll
      for (int i = 0; i < 4; ++i) {
        const int ra = wm * 64 + i * 16 + c;
        const int rb = wn * 64 + i * 16 + c;
        af[i]  = *(const s16x8_a*)(As + ra * 64 + ((ks * 4 + g) ^ (ra & 7)) * 8);
        bfr[i] = *(const s16x8_a*)(Bs + rb * 64 + ((ks * 4 + g) ^ (rb & 7)) * 8);
      }
      #pragma unroll
      for (int mf = 0; mf < 4; ++mf)
        #pragma unroll
        for (int nf = 0; nf < 4; ++nf)
          acc[mf][nf] = mfma16(af[mf], bfr[nf], acc[mf][nf]);
    }
  }

  #pragma unroll
  for (int nf = 0; nf < 4; ++nf) {
    const int n = n0 + wn * 64 + nf * 16 + c;
    const float bv = bias[n];
    #pragma unroll
    for (int mf = 0; mf < 4; ++mf)
      #pragma unroll
      for (int r = 0; r < 4; ++r) {
        const int m = m0 + wm * 64 + mf * 16 + g * 4 + r;
        const float v = (acc[mf][nf][r] + bv) * qs;
        if (MODE == 0) {
          oF[(size_t)m * 512 + n] = v;
        } else {
          const int bb = m >> 12, s = m & 4095, h = n >> 6, hd = n & 63;
          if (z == 2)
            outb[(((size_t)(bb * 8 + h)) * 64 + hd) * 4096 + s] = f2bf(v);
          else
            outb[(((size_t)(bb * 8 + h)) * 4096 + s) * 64 + hd] = f2bf(v);
        }
      }
  }
}

// ---------------- flash attention v11 (round-2 proven: 102us, deterministic) ----------------
// 32 q-rows/wave, 256 threads, __syncthreads-dbuf (full drain -> race-free),
// XCD remap (KV L2-resident), XOR-swizzled K/V staging via global_load_lds,
// Ps wave-local, l = P.1 on the MFMA pipe, Q pre-scaled by sc*log2e.
// v12 (SW pipeline) and v13 (counted vmcnt) were neutral; v13's asm-barrier
// pattern is implicated in the round-5 tripwire -> reverted to this version.
// attn residual (~103us, MfmaUtil ~31%) is a co-designed-structure gap
// (T16-class), invariant to every single-lever fix tried (r0-r3).
__global__ __launch_bounds__(256, 2) void attn(const USH* __restrict__ Qbuf,
                                               const USH* __restrict__ kv,
                                               USH* __restrict__ att) {
  __shared__ __align__(16) USH Ks[2 * 4096];   // [buf][half*64+key][32 USH]
  __shared__ __align__(16) USH Vt[2 * 4096];   // [buf][64 hd][64 USH]
  __shared__ __align__(16) USH Ps[4][32 * 76]; // per-wave [32 qrow][76 key-pad]
  __shared__ float lbuf[4][32];

  const int t = threadIdx.x;
  const int w = t >> 6, lane = t & 63;
  const int c = lane & 15, g = lane >> 4;
  // XCD-aware remap: each XCD owns 2 bh -> KV working set 2 MB <= L2.
  const int linear = blockIdx.x + (blockIdx.y << 5);
  const int xcd = linear & 7, idx = linear >> 3;
  const int bh = xcd + ((idx >> 5) << 3);
  const int bb = bh >> 3, hh = bh & 7;
  const size_t base = (size_t)bh * 262144;  // 4096*64
  const USH* Q = Qbuf + base;
  const USH* K = kv + base;                 // [S,Hd]
  const USH* V = kv + 4194304 + base;       // [Hd,S] (pre-transposed)
  const int q0 = (idx & 31) * 128 + w * 32;

  // Q fragments (B-operand of S^T): registers for the whole K loop
  s16x8 qf[2][2];  // [qi][kh]
  #pragma unroll
  for (int qi = 0; qi < 2; ++qi)
    #pragma unroll
    for (int kh = 0; kh < 2; ++kh)
      qf[qi][kh] = *(const s16x8_a*)(Q + (size_t)(q0 + qi * 16 + c) * 64 + kh * 32 + g * 8);

  // constant ones-column B-fragment: l = P . 1 on the MFMA pipe
  s16x8 onesf;
  {
    const short one = (short)0x3F80, val = (c == 0) ? one : (short)0;
    #pragma unroll
    for (int j = 0; j < 8; ++j) onesf[j] = val;
  }

  f32x4 o[2][4] = {};
  f32x4 o_l[2] = {};

  // --- DMA lane mappings (4 waves -> 2 calls per tile) ---
  const int keyK = w * 16 + (lane >> 2);
  const int ccK = (lane & 3) ^ ((keyK >> 1) & 3);
  const USH* gK0 = K + (size_t)keyK * 64 + ccK * 8;   // +kt*4096 +j*32
  const int hdV = w * 8 + (lane >> 3);
  const int ccV = (lane & 7) ^ (hdV & 7);
  const USH* gV0 = V + (size_t)hdV * 4096 + ccV * 8;  // +kt*64 +j*32*4096
  USH* lK = Ks + w * 512 + lane * 8;   // +buf*4096 +j*2048
  USH* lV = Vt + w * 512 + lane * 8;   // +buf*4096 +j*2048

  // issue tile 0 -> buf 0
  #pragma unroll
  for (int j = 0; j < 2; ++j) {
    gld_lds16(gK0 + j * 32, lK + j * 2048);
    gld_lds16(gV0 + (size_t)j * 131072, lV + j * 2048);
  }

  for (int kt = 0; kt < 64; ++kt) {
    const int buf = kt & 1;
    __syncthreads();  // implicit vmcnt(0): tile kt resident; buf^1 free
    if (kt < 63) {    // issue tile kt+1 -> buf^1; flies across this iteration
      const int nb = (buf ^ 1) * 4096;
      #pragma unroll
      for (int j = 0; j < 2; ++j) {
        gld_lds16(gK0 + (size_t)(kt + 1) * 4096 + j * 32, lK + nb + j * 2048);
        gld_lds16(gV0 + (size_t)(kt + 1) * 64 + (size_t)j * 131072, lV + nb + j * 2048);
      }
    }

    // S^T[key][qrow] = K * Q^T  (Q pre-scaled; st IS the exp2 argument)
    f32x4 st[2][4] = {};
    #pragma unroll
    for (int kh = 0; kh < 2; ++kh) {
      s16x8 ak[4];
      #pragma unroll
      for (int kff = 0; kff < 4; ++kff) {
        const int row = kff * 16 + c;
        const int qsw = (g ^ ((c >> 1) & 3)) * 8;
        ak[kff] = *(const s16x8_a*)(Ks + buf * 4096 + kh * 2048 + row * 32 + qsw);
      }
      #pragma unroll
      for (int qi = 0; qi < 2; ++qi)
        #pragma unroll
        for (int kff = 0; kff < 4; ++kff)
          st[qi][kff] = mfma16(ak[kff], qf[qi][kh], st[qi][kff]);
    }

    // p = exp2(s)
    #pragma unroll
    for (int qi = 0; qi < 2; ++qi)
      #pragma unroll
      for (int kff = 0; kff < 4; ++kff)
        #pragma unroll
        for (int r = 0; r < 4; ++r)
          st[qi][kff][r] = EXP2F(st[qi][kff][r]);

    // write P to Ps[w][qrow][key] (wave-local; in-order DS, no barrier)
    #pragma unroll
    for (int qi = 0; qi < 2; ++qi)
      #pragma unroll
      for (int kff = 0; kff < 4; ++kff) {
        const unsigned int lo = pk_bf16(st[qi][kff][0], st[qi][kff][1]);
        const unsigned int hi = pk_bf16(st[qi][kff][2], st[qi][kff][3]);
        *(u64_a*)(&Ps[w][(qi * 16 + c) * 76 + kff * 16 + g * 4]) =
            (unsigned long long)lo | ((unsigned long long)hi << 32);
      }

    // O[qrow][hd] += P * V ; l[qrow] += P . 1
    #pragma unroll
    for (int kf = 0; kf < 2; ++kf) {
      s16x8 ap[2];
      #pragma unroll
      for (int qi = 0; qi < 2; ++qi)
        ap[qi] = *(const s16x8_a*)(&Ps[w][(qi * 16 + c) * 76 + kf * 32 + g * 8]);
      s16x8 bv[4];
      #pragma unroll
      for (int hf = 0; hf < 4; ++hf) {
        const int qv = ((kf * 4 + g) ^ (c & 7)) * 8;
        bv[hf] = *(const s16x8_a*)(Vt + buf * 4096 + (c + 16 * hf) * 64 + qv);
      }
      #pragma unroll
      for (int qi = 0; qi < 2; ++qi) {
        #pragma unroll
        for (int hf = 0; hf < 4; ++hf)
          o[qi][hf] = mfma16(ap[qi], bv[hf], o[qi][hf]);
        o_l[qi] = mfma16(ap[qi], onesf, o_l[qi]);
      }
    }
  }

  // l lives in lanes c==0 (D[m][0]); broadcast within the wave via LDS
  if (c == 0) {
    #pragma unroll
    for (int qi = 0; qi < 2; ++qi)
      #pragma unroll
      for (int r = 0; r < 4; ++r) lbuf[w][qi * 16 + g * 4 + r] = o_l[qi][r];
  }
  __syncthreads();

  #pragma unroll
  for (int qi = 0; qi < 2; ++qi)
    #pragma unroll
    for (int r = 0; r < 4; ++r) {
      const int ml = qi * 16 + g * 4 + r;
      const float linv = 1.0f / lbuf[w][ml];
      const int qrow = q0 + ml;
      #pragma unroll
      for (int hf = 0; hf < 4; ++hf) {
        const int hd = c + 16 * hf;
        att[((size_t)(bb * 4096 + qrow)) * 512 + hh * 64 + hd] =
            f2bf(o[qi][hf][r] * linv);
      }
    }
}

extern "C" void kernel_launch(void* const* d_in, const int* in_sizes, int n_in,
                              void* d_out, int out_size, void* d_ws, size_t ws_size,
                              hipStream_t stream) {
  (void)in_sizes; (void)n_in; (void)out_size; (void)ws_size;
  const float* x  = (const float*)d_in[0];
  const float* Wq = (const float*)d_in[1];
  const float* bq = (const float*)d_in[2];
  const float* Wk = (const float*)d_in[3];
  const float* bk = (const float*)d_in[4];
  const float* Wv = (const float*)d_in[5];
  const float* bv = (const float*)d_in[6];
  const float* Wo = (const float*)d_in[7];
  const float* bo = (const float*)d_in[8];
  USH* ws  = (USH*)d_ws;
  USH* wT  = ws;                       // 4 * 262144 bf16 transposed weights (2 MB)
  USH* kv  = ws + 1048576;             // K [B,H,S,Hd] + V [B,H,Hd,S] bf16 (16 MB)
  USH* att = ws + 1048576 + 8388608;   // 4194304 : attn out [B,S,D] bf16 (8 MB)
  float* outF = (float*)d_out;         // fp32 output (16 MB)
  USH* qscratch = (USH*)d_out;         // Q bf16 (8 MB), dead before final GEMM
  USH* xb = (USH*)d_out + 4194304;     // x bf16 (8 MB), dead before final GEMM

  prep<<<dim3(16, 16, 5), 256, 0, stream>>>(Wq, Wk, Wv, Wo, x, wT, xb);
  gemm_bias<1><<<dim3(64, 4, 3), 256, 0, stream>>>(xb, wT, bq, bk, bv,
                                                   qscratch, kv, nullptr);
  attn<<<dim3(32, 16), 256, 0, stream>>>(qscratch, kv, att);
  gemm_bias<0><<<dim3(64, 4, 1), 256, 0, stream>>>(att, wT + 3 * 262144, bo, bo, bo,
                                                   nullptr, nullptr, outF);
}

// Round 7
// 199.880 us; speedup vs baseline: 1.0734x; 1.0504x over previous
//
#include <hip/hip_runtime.h>

typedef unsigned short USH;
typedef short s16x8 __attribute__((ext_vector_type(8)));
typedef float f32x4 __attribute__((ext_vector_type(4)));
typedef float f32x4v __attribute__((ext_vector_type(4)));
typedef unsigned int u32x4 __attribute__((ext_vector_type(4)));
// may_alias variants for ALL type-punned LDS/global accesses.
typedef s16x8 s16x8_a __attribute__((may_alias));
typedef f32x4v f32x4v_a __attribute__((may_alias));
typedef u32x4 u32x4_a __attribute__((may_alias));
typedef unsigned long long u64_a __attribute__((may_alias));

#if __has_builtin(__builtin_amdgcn_exp2f)
#define EXP2F(x) __builtin_amdgcn_exp2f(x)  // raw v_exp_f32, no legalization
#else
#define EXP2F(x) __builtin_exp2f(x)
#endif

__device__ __forceinline__ USH f2bf(float f) {
  union { float f; unsigned int i; } c; c.f = f;
  unsigned int x = c.i;
  return (USH)((x + 0x7FFFu + ((x >> 16) & 1u)) >> 16);
}
__device__ __forceinline__ unsigned int pk_bf16(float a, float b) {
#if __has_builtin(__builtin_amdgcn_cvt_pk_bf16_f32)
  typedef USH ush2 __attribute__((ext_vector_type(2)));
  union { ush2 v; unsigned int u; } r;
  r.v = __builtin_amdgcn_cvt_pk_bf16_f32(a, b);
  return r.u;
#else
  union { float f; unsigned int i; } ca, cb; ca.f = a; cb.f = b;
  return ((ca.i + 0x8000u) >> 16) | ((cb.i + 0x8000u) & 0xFFFF0000u);
#endif
}

__device__ __forceinline__ f32x4 mfma16(s16x8 a, s16x8 b, f32x4 c) {
  return __builtin_amdgcn_mfma_f32_16x16x32_bf16(a, b, c, 0, 0, 0);
}

// async global->LDS, 16B per lane; LDS dest semantics: wave base + lane*16.
#if __has_builtin(__builtin_amdgcn_global_load_lds)
__device__ __forceinline__ void gld_lds16(const USH* g, USH* l) {
  __builtin_amdgcn_global_load_lds(
      static_cast<const unsigned int __attribute__((address_space(1)))*>(
          (const void __attribute__((address_space(1)))*)g),
      static_cast<unsigned int __attribute__((address_space(3)))*>(
          (void __attribute__((address_space(3)))*)l),
      16, 0, 0);
}
#else
__device__ __forceinline__ void gld_lds16(const USH* g, USH* l) {
  *(s16x8_a*)l = *(const s16x8_a*)g;  // fallback: synchronous copy, same addresses
}
#endif

// ------------- prep: z<4 -> WT[n][k] = bf16(W[k][n]);  z==4 -> xb = bf16(x) -------------
__global__ __launch_bounds__(256) void prep(
    const float* __restrict__ Wq, const float* __restrict__ Wk,
    const float* __restrict__ Wv, const float* __restrict__ Wo,
    const float* __restrict__ x, USH* __restrict__ wsT, USH* __restrict__ xb) {
  __shared__ float tile[32][33];
  const int z = blockIdx.z;
  const int t = threadIdx.x;
  if (z == 4) {  // convert x: 256 blocks x 16384 floats
    const size_t b0 = ((size_t)blockIdx.y * 16 + blockIdx.x) * 16384;
    #pragma unroll
    for (int j = 0; j < 8; ++j) {
      const size_t i = b0 + (size_t)j * 2048 + t * 8;
      const f32x4v a = *(const f32x4v_a*)(x + i);
      const f32x4v b = *(const f32x4v_a*)(x + i + 4);
      u32x4 s;
      s.x = pk_bf16(a.x, a.y); s.y = pk_bf16(a.z, a.w);
      s.z = pk_bf16(b.x, b.y); s.w = pk_bf16(b.z, b.w);
      *(u32x4_a*)(xb + i) = s;
    }
    return;
  }
  const float* W = (z == 0) ? Wq : (z == 1) ? Wk : (z == 2) ? Wv : Wo;
  USH* WT = wsT + (size_t)z * 262144;
  const int n0 = blockIdx.x * 32, k0 = blockIdx.y * 32;
  const int tx = t & 31, ty = t >> 5;  // 32 x 8
  #pragma unroll
  for (int i = 0; i < 4; ++i)
    tile[ty + i * 8][tx] = W[(size_t)(k0 + ty + i * 8) * 512 + n0 + tx];
  __syncthreads();
  #pragma unroll
  for (int i = 0; i < 4; ++i)
    WT[(size_t)(n0 + ty + i * 8) * 512 + k0 + tx] = f2bf(tile[tx][ty + i * 8]);
}

// ---------------- GEMM v3: out = A[M,512](bf16) * WT^T + bias ----------------
// (round-6 verified: passed tripwire, ~equal to reg-staged baseline; kept.)
// m97-proven single-buffer 2-barrier structure with global_load_lds staging,
// __syncthreads-only (deterministic). XOR-swizzle both-sides (rule #21).
// MODE 0: float out[m*512+n] (d_out fp32).
// MODE 1: z==0 -> Q bf16 [B,H,S,Hd] scaled by sc*log2e; z==1 -> K [B,H,S,Hd];
//         z==2 -> V [B,H,Hd,S] (pre-transposed for attn).
template <int MODE>
__global__ __launch_bounds__(256, 3) void gemm_bias(
    const USH* __restrict__ A, const USH* __restrict__ BT0,
    const float* __restrict__ b0, const float* __restrict__ b1,
    const float* __restrict__ b2,
    USH* __restrict__ oQ, USH* __restrict__ oKV, float* __restrict__ oF) {
  __shared__ __align__(16) USH As[8192];  // [128 rows][64 USH] chunk-swizzled
  __shared__ __align__(16) USH Bs[8192];
  const int z = blockIdx.z;
  const USH* BT = BT0 + (size_t)z * 262144;
  const float* bias = (z == 0) ? b0 : ((z == 1) ? b1 : b2);
  USH* outb = (z == 0) ? oQ : (oKV + (size_t)(z - 1) * 4194304);
  const float qs = (MODE == 1 && z == 0) ? 0.06375871528132839f : 1.0f;

  const int t = threadIdx.x;
  const int w = t >> 6, lane = t & 63;
  const int c = lane & 15, g = lane >> 4;
  const int wm = w & 1, wn = w >> 1;
  const int m0 = blockIdx.x * 128, n0 = blockIdx.y * 128;

  f32x4 acc[4][4] = {};

  const int rD = w * 32 + (lane >> 3);                       // +j*8
  const int ccD = (((lane & 7) ^ ((lane >> 3) & 7))) * 8;    // global chunk*8
  const USH* ApD = A + (size_t)(m0 + rD) * 512 + ccD;        // +kt*64 +j*4096
  const USH* BpD = BT + (size_t)(n0 + rD) * 512 + ccD;
  USH* lA = As + w * 2048 + lane * 8;                        // +j*512
  USH* lB = Bs + w * 2048 + lane * 8;

  for (int kt = 0; kt < 8; ++kt) {
    __syncthreads();  // full drain: previous COMPUTE's ds_reads done
    #pragma unroll
    for (int j = 0; j < 4; ++j) {
      gld_lds16(ApD + kt * 64 + j * 4096, lA + j * 512);
      gld_lds16(BpD + kt * 64 + j * 4096, lB + j * 512);
    }
    __syncthreads();  // full drain: DMA landed -> tile kt resident block-wide
    #pragma unroll
    for (int ks = 0; ks < 2; ++ks) {
      s16x8 af[4], bfr[4];
      #pragma unroll
      for (int i = 0; i < 4; ++i) {
        const int ra = wm * 64 + i * 16 + c;
        const int rb = wn * 64 + i * 16 + c;
        af[i]  = *(const s16x8_a*)(As + ra * 64 + ((ks * 4 + g) ^ (ra & 7)) * 8);
        bfr[i] = *(const s16x8_a*)(Bs + rb * 64 + ((ks * 4 + g) ^ (rb & 7)) * 8);
      }
      #pragma unroll
      for (int mf = 0; mf < 4; ++mf)
        #pragma unroll
        for (int nf = 0; nf < 4; ++nf)
          acc[mf][nf] = mfma16(af[mf], bfr[nf], acc[mf][nf]);
    }
  }

  #pragma unroll
  for (int nf = 0; nf < 4; ++nf) {
    const int n = n0 + wn * 64 + nf * 16 + c;
    const float bv = bias[n];
    #pragma unroll
    for (int mf = 0; mf < 4; ++mf)
      #pragma unroll
      for (int r = 0; r < 4; ++r) {
        const int m = m0 + wm * 64 + mf * 16 + g * 4 + r;
        const float v = (acc[mf][nf][r] + bv) * qs;
        if (MODE == 0) {
          oF[(size_t)m * 512 + n] = v;
        } else {
          const int bb = m >> 12, s = m & 4095, h = n >> 6, hd = n & 63;
          if (z == 2)
            outb[(((size_t)(bb * 8 + h)) * 64 + hd) * 4096 + s] = f2bf(v);
          else
            outb[(((size_t)(bb * 8 + h)) * 4096 + s) * 64 + hd] = f2bf(v);
        }
      }
  }
}

// ---------------- flash attention v14: KVBLK=128 (fixed-cost-per-iter probe) ----------------
// r0-r3 nulls: per-iter time ~3860 cyc invariant to memory level, LDS
// traffic, waves/SIMD, phase order, drain structure -- but EVERY variant kept
// 64 iterations of 64-key tiles. Hypothesis: time/iter is dominated by a
// work-independent fixed cost (barrier + DMA drain + chain refill). Probe:
// double tile to 128 keys, halve iterations to 32. Fixed-cost theory ->
// ~65-80us; work-bound -> unchanged ~103us (then attn is closed).
// 512 thr / 8 waves x 32 q-rows = 256 q-rows/block; grid (16 qt, 16 bh) =
// 256 blocks = 1/CU; 8 waves/CU = SAME waves/CU as v11 (not a confound).
// LDS: K dbuf 2x16K + V dbuf 2x16K + Ps 8x[32x140] 70K + lbuf 1K = 135 KB
// (gfx950 allows 160 KB/WG). Ps pad 140: dword row-stride 70 == 6 mod 32,
// same bank-spread class as v11's proven pad-76. Same XOR swizzles/DMA
// involutions, one __syncthreads per iter, deterministic by construction.
__global__ __launch_bounds__(512, 2) void attn(const USH* __restrict__ Qbuf,
                                               const USH* __restrict__ kv,
                                               USH* __restrict__ att) {
  __shared__ __align__(16) USH Ks[2 * 8192];    // [buf][half][key 0..127][32 USH]
  __shared__ __align__(16) USH Vt[2 * 8192];    // [buf][64 hd][128 USH]
  __shared__ __align__(16) USH Ps[8][32 * 140]; // per-wave [32 qrow][140 key-pad]
  __shared__ float lbuf[8][32];

  const int t = threadIdx.x;
  const int w = t >> 6, lane = t & 63;
  const int c = lane & 15, g = lane >> 4;
  // XCD-aware remap, bijective on [0,256): each XCD owns bh {xcd, xcd+8}
  // -> KV working set 2 MB <= per-XCD L2.
  const int linear = blockIdx.x + (blockIdx.y << 4);
  const int xcd = linear & 7, idx = linear >> 3;   // idx in [0,32)
  const int bh = xcd + ((idx >> 4) << 3);
  const int bb = bh >> 3, hh = bh & 7;
  const size_t base = (size_t)bh * 262144;  // 4096*64
  const USH* Q = Qbuf + base;
  const USH* K = kv + base;                 // [S,Hd]
  const USH* V = kv + 4194304 + base;       // [Hd,S] (pre-transposed)
  const int q0 = (idx & 15) * 256 + w * 32;

  // Q fragments (B-operand of S^T): registers for the whole K loop
  s16x8 qf[2][2];  // [qi][kh]
  #pragma unroll
  for (int qi = 0; qi < 2; ++qi)
    #pragma unroll
    for (int kh = 0; kh < 2; ++kh)
      qf[qi][kh] = *(const s16x8_a*)(Q + (size_t)(q0 + qi * 16 + c) * 64 + kh * 32 + g * 8);

  // constant ones-column B-fragment: l = P . 1 on the MFMA pipe
  s16x8 onesf;
  {
    const short one = (short)0x3F80, val = (c == 0) ? one : (short)0;
    #pragma unroll
    for (int j = 0; j < 8; ++j) onesf[j] = val;
  }

  f32x4 o[2][4] = {};
  f32x4 o_l[2] = {};

  // --- DMA lane mappings (8 waves, 2 calls each per K and V per tile) ---
  // K: inst (w,j): covers kh=j, key = w*16 + (lane>>2), phys chunk lane&3;
  //    source global chunk = (lane&3) ^ ((key>>1)&3)   (XOR involution)
  const int keyK = w * 16 + (lane >> 2);               // 0..127
  const int ccK = (lane & 3) ^ ((keyK >> 1) & 3);
  const USH* gK0 = K + (size_t)keyK * 64 + ccK * 8;    // +kt*8192 +j*32
  // V: inst (w,j): hd = j*32 + w*4 + (lane>>4), phys chunk lane&15;
  //    source global chunk = (lane&15) ^ (hd&7); hd&7 invariant in j.
  const int hdV = w * 4 + (lane >> 4);                 // 0..31, +j*32
  const int ccV = (lane & 15) ^ (hdV & 7);
  const USH* gV0 = V + (size_t)hdV * 4096 + ccV * 8;   // +kt*128 +j*131072
  USH* lK = Ks + w * 512 + lane * 8;   // +buf*8192 +j*4096
  USH* lV = Vt + w * 512 + lane * 8;   // +buf*8192 +j*4096

  // issue tile 0 -> buf 0
  #pragma unroll
  for (int j = 0; j < 2; ++j) {
    gld_lds16(gK0 + j * 32, lK + j * 4096);
    gld_lds16(gV0 + (size_t)j * 131072, lV + j * 4096);
  }

  for (int kt = 0; kt < 32; ++kt) {
    const int buf = kt & 1;
    __syncthreads();  // implicit vmcnt(0): tile kt resident; buf^1 free
    if (kt < 31) {    // issue tile kt+1 -> buf^1; flies across this iteration
      const int nb = (buf ^ 1) * 8192;
      #pragma unroll
      for (int j = 0; j < 2; ++j) {
        gld_lds16(gK0 + (size_t)(kt + 1) * 8192 + j * 32, lK + nb + j * 4096);
        gld_lds16(gV0 + (size_t)(kt + 1) * 128 + (size_t)j * 131072, lV + nb + j * 4096);
      }
    }

    // S^T[key][qrow] = K * Q^T  (Q pre-scaled; st IS the exp2 argument)
    f32x4 st[2][8] = {};
    #pragma unroll
    for (int kh = 0; kh < 2; ++kh) {
      s16x8 ak[8];
      #pragma unroll
      for (int kff = 0; kff < 8; ++kff) {
        const int row = kff * 16 + c;
        const int qsw = (g ^ ((c >> 1) & 3)) * 8;
        ak[kff] = *(const s16x8_a*)(Ks + buf * 8192 + kh * 4096 + row * 32 + qsw);
      }
      #pragma unroll
      for (int qi = 0; qi < 2; ++qi)
        #pragma unroll
        for (int kff = 0; kff < 8; ++kff)
          st[qi][kff] = mfma16(ak[kff], qf[qi][kh], st[qi][kff]);
    }

    // p = exp2(s); pack; write P to Ps[w] (wave-local; in-order DS)
    #pragma unroll
    for (int qi = 0; qi < 2; ++qi)
      #pragma unroll
      for (int kff = 0; kff < 8; ++kff) {
        #pragma unroll
        for (int r = 0; r < 4; ++r) st[qi][kff][r] = EXP2F(st[qi][kff][r]);
        const unsigned int lo = pk_bf16(st[qi][kff][0], st[qi][kff][1]);
        const unsigned int hi = pk_bf16(st[qi][kff][2], st[qi][kff][3]);
        *(u64_a*)(&Ps[w][(qi * 16 + c) * 140 + kff * 16 + g * 4]) =
            (unsigned long long)lo | ((unsigned long long)hi << 32);
      }

    // O[qrow][hd] += P * V ; l[qrow] += P . 1
    #pragma unroll
    for (int kf = 0; kf < 4; ++kf) {
      s16x8 ap[2];
      #pragma unroll
      for (int qi = 0; qi < 2; ++qi)
        ap[qi] = *(const s16x8_a*)(&Ps[w][(qi * 16 + c) * 140 + kf * 32 + g * 8]);
      s16x8 bv[4];
      #pragma unroll
      for (int hf = 0; hf < 4; ++hf) {
        const int qv = (((kf * 4 + g) ^ (c & 7))) * 8;
        bv[hf] = *(const s16x8_a*)(Vt + buf * 8192 + (c + 16 * hf) * 128 + qv);
      }
      #pragma unroll
      for (int qi = 0; qi < 2; ++qi) {
        #pragma unroll
        for (int hf = 0; hf < 4; ++hf)
          o[qi][hf] = mfma16(ap[qi], bv[hf], o[qi][hf]);
        o_l[qi] = mfma16(ap[qi], onesf, o_l[qi]);
      }
    }
  }

  // l lives in lanes c==0 (D[m][0]); broadcast within the wave via LDS
  if (c == 0) {
    #pragma unroll
    for (int qi = 0; qi < 2; ++qi)
      #pragma unroll
      for (int r = 0; r < 4; ++r) lbuf[w][qi * 16 + g * 4 + r] = o_l[qi][r];
  }
  __syncthreads();

  #pragma unroll
  for (int qi = 0; qi < 2; ++qi)
    #pragma unroll
    for (int r = 0; r < 4; ++r) {
      const int ml = qi * 16 + g * 4 + r;
      const float linv = 1.0f / lbuf[w][ml];
      const int qrow = q0 + ml;
      #pragma unroll
      for (int hf = 0; hf < 4; ++hf) {
        const int hd = c + 16 * hf;
        att[((size_t)(bb * 4096 + qrow)) * 512 + hh * 64 + hd] =
            f2bf(o[qi][hf][r] * linv);
      }
    }
}

extern "C" void kernel_launch(void* const* d_in, const int* in_sizes, int n_in,
                              void* d_out, int out_size, void* d_ws, size_t ws_size,
                              hipStream_t stream) {
  (void)in_sizes; (void)n_in; (void)out_size; (void)ws_size;
  const float* x  = (const float*)d_in[0];
  const float* Wq = (const float*)d_in[1];
  const float* bq = (const float*)d_in[2];
  const float* Wk = (const float*)d_in[3];
  const float* bk = (const float*)d_in[4];
  const float* Wv = (const float*)d_in[5];
  const float* bv = (const float*)d_in[6];
  const float* Wo = (const float*)d_in[7];
  const float* bo = (const float*)d_in[8];
  USH* ws  = (USH*)d_ws;
  USH* wT  = ws;                       // 4 * 262144 bf16 transposed weights (2 MB)
  USH* kv  = ws + 1048576;             // K [B,H,S,Hd] + V [B,H,Hd,S] bf16 (16 MB)
  USH* att = ws + 1048576 + 8388608;   // 4194304 : attn out [B,S,D] bf16 (8 MB)
  float* outF = (float*)d_out;         // fp32 output (16 MB)
  USH* qscratch = (USH*)d_out;         // Q bf16 (8 MB), dead before final GEMM
  USH* xb = (USH*)d_out + 4194304;     // x bf16 (8 MB), dead before final GEMM

  prep<<<dim3(16, 16, 5), 256, 0, stream>>>(Wq, Wk, Wv, Wo, x, wT, xb);
  gemm_bias<1><<<dim3(64, 4, 3), 256, 0, stream>>>(xb, wT, bq, bk, bv,
                                                   qscratch, kv, nullptr);
  attn<<<dim3(16, 16), 512, 0, stream>>>(qscratch, kv, att);
  gemm_bias<0><<<dim3(64, 4, 1), 256, 0, stream>>>(att, wT + 3 * 262144, bo, bo, bo,
                                                   nullptr, nullptr, outF);
}